// Round 16
// baseline (92.696 us; speedup 1.0000x reference)
//
#include <hip/hip_runtime.h>
#include <math.h>

#define L_SEQ 8192
#define B_N   8

typedef float f4v __attribute__((ext_vector_type(4)));

// Workspace layout (float offsets); ~8.7 MB used.
#define QKV_OFF    0                        // [8][512] = 4096 (pre-scaled by 0.125)
#define V_OFF      4096                     // [8][512] = 4096
#define ROW_OFF    8192                     // [8][512] = 4096
#define QFP_OFF    12288                    // [53][512] = 27136 (qf partials)
#define DPART_OFF  40960                    // [512 slots][8] = 4096
#define YPART_OFF  65536                    // [512 slots][4096] = 2097152

// ---- k2: self-contained qf partials: recompute qraw slice in-block, no atomics ----
__global__ __launch_bounds__(512) void k2_qf(const float* __restrict__ poi,
                                             const float* __restrict__ wq1,
                                             const float* __restrict__ bq1,
                                             const float* __restrict__ wq2, float* ws) {
    __shared__ float qr[32];
    int k = blockIdx.x, t = threadIdx.x;
    int i0 = k * 32;
    int cnt = 1683 - i0; if (cnt > 32) cnt = 32;
    if (t < cnt) {
        float a = bq1[0];
#pragma unroll
        for (int j = 0; j < 24; ++j) a += poi[(i0 + t) * 24 + j] * wq1[j];
        qr[t] = a;
    }
    __syncthreads();
    float a = 0.f;
    for (int ii = 0; ii < cnt; ++ii) a += qr[ii] * wq2[(size_t)(i0 + ii) * 512 + t];
    ws[QFP_OFF + k * 512 + t] = a;
}

// ---- k3: qf = bq2 + sum partials; qkvec (pre-scaled); blocks 0-7 init V=bv, 8-15 row=bo ----
__global__ void k3_qkvec(const float* __restrict__ wk, const float* __restrict__ bq2,
                         const float* __restrict__ bv, const float* __restrict__ bo, float* ws) {
    __shared__ float qf[512];
    int t = threadIdx.x, bid = blockIdx.x;
    for (int o = t; o < 512; o += 256) {
        float s = bq2[o];
        for (int k = 0; k < 53; ++k) s += ws[QFP_OFF + k * 512 + o];
        qf[o] = s;
    }
    __syncthreads();
    int idx = bid * 256 + t;
    int h = idx >> 9, c = idx & 511;
    float a = 0.f;
#pragma unroll 8
    for (int e = 0; e < 64; ++e) a += qf[h * 64 + e] * wk[(size_t)c * 512 + h * 64 + e];
    ws[QKV_OFF + idx] = 0.125f * a;
    if (bid < 8) {
        ws[V_OFF + bid * 512 + t]       = bv[t];
        ws[V_OFF + bid * 512 + 256 + t] = bv[256 + t];
    } else {
        int b = bid - 8;
        ws[ROW_OFF + b * 512 + t]       = bo[t];
        ws[ROW_OFF + b * 512 + 256 + t] = bo[256 + t];
    }
}

// ---- helper: fold-by-head butterfly for a pair of rows (R12/R13/R15-verified) ----
__device__ __forceinline__ void fold_pair(const float p1[8], const float p2[8],
                                          int b0, int b1, int b2,
                                          float& sA, float& sB) {
    float a0 = b0 ? p1[1] : p1[0], t0 = b0 ? p1[0] : p1[1];
    float a1 = b0 ? p1[3] : p1[2], t1 = b0 ? p1[2] : p1[3];
    float a2 = b0 ? p1[5] : p1[4], t2 = b0 ? p1[4] : p1[5];
    float a3 = b0 ? p1[7] : p1[6], t3 = b0 ? p1[6] : p1[7];
    float c0 = b0 ? p2[1] : p2[0], u0 = b0 ? p2[0] : p2[1];
    float c1 = b0 ? p2[3] : p2[2], u1 = b0 ? p2[2] : p2[3];
    float c2 = b0 ? p2[5] : p2[4], u2 = b0 ? p2[4] : p2[5];
    float c3 = b0 ? p2[7] : p2[6], u3 = b0 ? p2[6] : p2[7];
    float vA0 = a0 + __shfl_xor(t0, 1, 64);
    float vA1 = a1 + __shfl_xor(t1, 1, 64);
    float vA2 = a2 + __shfl_xor(t2, 1, 64);
    float vA3 = a3 + __shfl_xor(t3, 1, 64);
    float vB0 = c0 + __shfl_xor(u0, 1, 64);
    float vB1 = c1 + __shfl_xor(u1, 1, 64);
    float vB2 = c2 + __shfl_xor(u2, 1, 64);
    float vB3 = c3 + __shfl_xor(u3, 1, 64);
    float wA0 = b1 ? vA1 : vA0, sA0 = b1 ? vA0 : vA1;
    float wA1 = b1 ? vA3 : vA2, sA1 = b1 ? vA2 : vA3;
    float wB0 = b1 ? vB1 : vB0, sB0 = b1 ? vB0 : vB1;
    float wB1 = b1 ? vB3 : vB2, sB1 = b1 ? vB2 : vB3;
    float uA0 = wA0 + __shfl_xor(sA0, 2, 64);
    float uA1 = wA1 + __shfl_xor(sA1, 2, 64);
    float uB0 = wB0 + __shfl_xor(sB0, 2, 64);
    float uB1 = wB1 + __shfl_xor(sB1, 2, 64);
    float zA = b2 ? uA1 : uA0, yA = b2 ? uA0 : uA1;
    float zB = b2 ? uB1 : uB0, yB = b2 ? uB0 : uB1;
    sA = zA + __shfl_xor(yA, 4, 64);
    sB = zB + __shfl_xor(yB, 4, 64);
    sA += __shfl_xor(sA, 8, 64);  sB += __shfl_xor(sB, 8, 64);
    sA += __shfl_xor(sA, 16, 64); sB += __shfl_xor(sB, 16, 64);
    sA += __shfl_xor(sA, 32, 64); sB += __shfl_xor(sB, 32, 64);
}

// ---- kF: fused pass, 4 rows/iteration (MLP-4: 16 float4 loads in flight),
// butterfly in two ILP-2 pairs. (256,2) = only proven no-spill big-regfile config.
__global__ __launch_bounds__(256, 2) void kF(const float* __restrict__ x, float* __restrict__ ws) {
    __shared__ float num_s[4096];
    __shared__ float den_s[8];
    int t = threadIdx.x;
    int lane = t & 63, w = t >> 6;        // 4 waves
    int b = blockIdx.x >> 6, slot = blockIdx.x & 63;
    int wslot = slot * 4 + w;             // 0..255 row streams per batch

    float4 qa[8], qb[8];
    {
        const float4* qg4 = (const float4*)(ws + QKV_OFF);
#pragma unroll
        for (int h = 0; h < 8; ++h) {
            qa[h] = qg4[h * 128 + lane * 2];
            qb[h] = qg4[h * 128 + lane * 2 + 1];
        }
    }

    const int b0 = lane & 1, b1 = (lane >> 1) & 1, b2 = (lane >> 2) & 1;
    float num[8][8] = {{0.f}};
    float den_own = 0.f;                  // running sum for head (lane&7)

    const float4* xp = (const float4*)(x + (size_t)b * L_SEQ * 512);

    for (int r = wslot; r < L_SEQ; r += 1024) {    // 8 iters; rows r, r+256, r+512, r+768
        // issue all 16 loads up front (MLP)
        float4 xa1 = xp[(size_t)(r      ) * 128 + lane * 2];
        float4 xb1 = xp[(size_t)(r      ) * 128 + lane * 2 + 1];
        float4 xa2 = xp[(size_t)(r + 256) * 128 + lane * 2];
        float4 xb2 = xp[(size_t)(r + 256) * 128 + lane * 2 + 1];
        float4 xa3 = xp[(size_t)(r + 512) * 128 + lane * 2];
        float4 xb3 = xp[(size_t)(r + 512) * 128 + lane * 2 + 1];
        float4 xa4 = xp[(size_t)(r + 768) * 128 + lane * 2];
        float4 xb4 = xp[(size_t)(r + 768) * 128 + lane * 2 + 1];

        float p1[8], p2[8];
#pragma unroll
        for (int h = 0; h < 8; ++h) {
            p1[h] = xa1.x * qa[h].x + xa1.y * qa[h].y + xa1.z * qa[h].z + xa1.w * qa[h].w
                  + xb1.x * qb[h].x + xb1.y * qb[h].y + xb1.z * qb[h].z + xb1.w * qb[h].w;
            p2[h] = xa2.x * qa[h].x + xa2.y * qa[h].y + xa2.z * qa[h].z + xa2.w * qa[h].w
                  + xb2.x * qb[h].x + xb2.y * qb[h].y + xb2.z * qb[h].z + xb2.w * qb[h].w;
        }
        float sA, sB;
        fold_pair(p1, p2, b0, b1, b2, sA, sB);
        float wgA = __expf(sA), wgB = __expf(sB);
        den_own += wgA + wgB;
        float wa[8], wb[8];
#pragma unroll
        for (int h = 0; h < 8; ++h) { wa[h] = __shfl(wgA, h, 64); wb[h] = __shfl(wgB, h, 64); }

        // second pair's dot products (overlaps first pair's accumulate below)
        float p3[8], p4[8];
#pragma unroll
        for (int h = 0; h < 8; ++h) {
            p3[h] = xa3.x * qa[h].x + xa3.y * qa[h].y + xa3.z * qa[h].z + xa3.w * qa[h].w
                  + xb3.x * qb[h].x + xb3.y * qb[h].y + xb3.z * qb[h].z + xb3.w * qb[h].w;
            p4[h] = xa4.x * qa[h].x + xa4.y * qa[h].y + xa4.z * qa[h].z + xa4.w * qa[h].w
                  + xb4.x * qb[h].x + xb4.y * qb[h].y + xb4.z * qb[h].z + xb4.w * qb[h].w;
        }
#pragma unroll
        for (int h = 0; h < 8; ++h) {
            num[h][0] += wa[h] * xa1.x + wb[h] * xa2.x;
            num[h][1] += wa[h] * xa1.y + wb[h] * xa2.y;
            num[h][2] += wa[h] * xa1.z + wb[h] * xa2.z;
            num[h][3] += wa[h] * xa1.w + wb[h] * xa2.w;
            num[h][4] += wa[h] * xb1.x + wb[h] * xb2.x;
            num[h][5] += wa[h] * xb1.y + wb[h] * xb2.y;
            num[h][6] += wa[h] * xb1.z + wb[h] * xb2.z;
            num[h][7] += wa[h] * xb1.w + wb[h] * xb2.w;
        }
        float sC, sD;
        fold_pair(p3, p4, b0, b1, b2, sC, sD);
        float wgC = __expf(sC), wgD = __expf(sD);
        den_own += wgC + wgD;
        float wc[8], wd[8];
#pragma unroll
        for (int h = 0; h < 8; ++h) { wc[h] = __shfl(wgC, h, 64); wd[h] = __shfl(wgD, h, 64); }
#pragma unroll
        for (int h = 0; h < 8; ++h) {
            num[h][0] += wc[h] * xa3.x + wd[h] * xa4.x;
            num[h][1] += wc[h] * xa3.y + wd[h] * xa4.y;
            num[h][2] += wc[h] * xa3.z + wd[h] * xa4.z;
            num[h][3] += wc[h] * xa3.w + wd[h] * xa4.w;
            num[h][4] += wc[h] * xb3.x + wd[h] * xb4.x;
            num[h][5] += wc[h] * xb3.y + wd[h] * xb4.y;
            num[h][6] += wc[h] * xb3.z + wd[h] * xb4.z;
            num[h][7] += wc[h] * xb3.w + wd[h] * xb4.w;
        }
    }

    // staged deterministic block reduction across the 4 waves
    for (int wi = 0; wi < 4; ++wi) {
        if (w == wi) {
#pragma unroll
            for (int h = 0; h < 8; ++h) {
                int base = h * 512 + lane * 8;
                if (wi == 0) {
#pragma unroll
                    for (int j = 0; j < 8; ++j) num_s[base + j] = num[h][j];
                } else {
#pragma unroll
                    for (int j = 0; j < 8; ++j) num_s[base + j] += num[h][j];
                }
            }
            if (lane < 8) { if (wi == 0) den_s[lane] = den_own; else den_s[lane] += den_own; }
        }
        __syncthreads();
    }
    // coalesced partial-slot store (no atomics)
    float4* yp4 = (float4*)(ws + YPART_OFF + (size_t)blockIdx.x * 4096);
    const float4* ns4 = (const float4*)num_s;
#pragma unroll
    for (int k = 0; k < 4; ++k) yp4[k * 256 + t] = ns4[k * 256 + t];
    if (t < 8) ws[DPART_OFF + blockIdx.x * 8 + t] = den_s[t];
}

// ---- kV: reduce 64 partial slots, normalize, V[b,o] += chunk GEMV (V init'd to bv) ----
__global__ __launch_bounds__(512) void kV(const float* __restrict__ wv, float* ws) {
    __shared__ float red[512];
    __shared__ float yn_s[512];   // [h][64c] for this chunk
    __shared__ float dinv[8];
    int b = blockIdx.x >> 3, cc = blockIdx.x & 7;
    int c0 = cc * 64;
    int t = threadIdx.x;
    red[t] = ws[DPART_OFF + (size_t)(b * 64 + (t >> 3)) * 8 + (t & 7)];
    __syncthreads();
#pragma unroll
    for (int off = 256; off >= 8; off >>= 1) {
        if (t < off) red[t] += red[t + off];
        __syncthreads();
    }
    if (t < 8) dinv[t] = 1.f / red[t];
    int h = t >> 6, cl = t & 63;
    float s = 0.f;
    const float* yp = ws + YPART_OFF + (size_t)(b * 64) * 4096 + h * 512 + c0 + cl;
#pragma unroll 8
    for (int sl = 0; sl < 64; ++sl) s += yp[(size_t)sl * 4096];
    __syncthreads();
    yn_s[t] = s * dinv[h];
    __syncthreads();
    int o = t, ho = o >> 6;
    const float* yh = yn_s + ho * 64;
    float acc = 0.f;
#pragma unroll 8
    for (int ci = 0; ci < 64; ++ci) acc += yh[ci] * wv[(size_t)(c0 + ci) * 512 + o];
    atomicAdd(ws + V_OFF + b * 512 + o, acc);
}

// ---- kRow: row[b,j] += sum_{o in chunk} V[b,o]*wo[o,j]  (row init'd to bo) ----
__global__ __launch_bounds__(512) void kRow(const float* __restrict__ wo, float* ws) {
    __shared__ float V_s[64];
    int b = blockIdx.x >> 3, oc = blockIdx.x & 7;
    int o0 = oc * 64;
    int t = threadIdx.x;
    if (t < 64) V_s[t] = ws[V_OFF + b * 512 + o0 + t];
    __syncthreads();
    float acc = 0.f;
#pragma unroll 8
    for (int oi = 0; oi < 64; ++oi) acc += V_s[oi] * wo[(size_t)(o0 + oi) * 512 + t];
    atomicAdd(ws + ROW_OFF + b * 512 + t, acc);
}

// ---- k9: broadcast out[b,l,:] = row[b,:]  (nontemporal float4 stores) ----
__global__ __launch_bounds__(256) void k9_out(const float* __restrict__ ws, float* __restrict__ out) {
    const f4v* row4 = (const f4v*)(ws + ROW_OFF);
    f4v* out4 = (f4v*)out;
    size_t stride = (size_t)gridDim.x * blockDim.x;
    for (size_t g = (size_t)blockIdx.x * blockDim.x + threadIdx.x; g < 8388608ull; g += stride) {
        int b = (int)(g >> 20);          // 8192 rows * 128 float4/row = 2^20 per batch
        int q = (int)(g & 127);
        f4v v = row4[b * 128 + q];
        __builtin_nontemporal_store(v, &out4[g]);
    }
}

extern "C" void kernel_launch(void* const* d_in, const int* in_sizes, int n_in,
                              void* d_out, int out_size, void* d_ws, size_t ws_size,
                              hipStream_t stream) {
    const float* x   = (const float*)d_in[0];
    const float* poi = (const float*)d_in[1];
    const float* wq1 = (const float*)d_in[2];
    const float* bq1 = (const float*)d_in[3];
    const float* wq2 = (const float*)d_in[4];
    const float* bq2 = (const float*)d_in[5];
    const float* wk  = (const float*)d_in[6];
    const float* bk  = (const float*)d_in[7];
    const float* wv  = (const float*)d_in[8];
    const float* bv  = (const float*)d_in[9];
    const float* wo  = (const float*)d_in[10];
    const float* bo  = (const float*)d_in[11];
    float* ws  = (float*)d_ws;
    float* out = (float*)d_out;
    (void)bk;

    k2_qf<<<53, 512, 0, stream>>>(poi, wq1, bq1, wq2, ws);
    k3_qkvec<<<16, 256, 0, stream>>>(wk, bq2, bv, bo, ws);
    kF<<<512, 256, 0, stream>>>(x, ws);
    kV<<<64, 512, 0, stream>>>(wv, ws);
    kRow<<<64, 512, 0, stream>>>(wo, ws);
    k9_out<<<2048, 256, 0, stream>>>(ws, out);
}

// Round 17
// 84.658 us; speedup vs baseline: 1.0950x; 1.0950x over previous
//
#include <hip/hip_runtime.h>
#include <math.h>

#define L_SEQ 8192
#define B_N   8

typedef float f4v __attribute__((ext_vector_type(4)));

// Workspace layout (float offsets); ~8.7 MB used.
#define QKV_OFF    0                        // [8][512] = 4096 (pre-scaled by 0.125)
#define ROW_OFF    8192                     // [8][512] = 4096
#define QFP_OFF    12288                    // [53][512] = 27136 (qf partials)
#define DPART_OFF  40960                    // [512 slots][8] = 4096
#define YPART_OFF  65536                    // [512 slots][4096] = 2097152

// DPP-fused add: keep + dpp<CTRL>(send).  ctrl: 0xB1=quad xor1, 0x4E=quad xor2,
// 0x128=row_ror:8 (== xor8 within a 16-lane row).
#define DPPADD(keep, send, CTRL) \
    ((keep) + __int_as_float(__builtin_amdgcn_update_dpp(0, __float_as_int(send), (CTRL), 0xF, 0xF, true)))
#define SWZADD(v, PAT) ((v) + __int_as_float(__builtin_amdgcn_ds_swizzle(__float_as_int(v), (PAT))))
#define SWZ(v, PAT)    (__int_as_float(__builtin_amdgcn_ds_swizzle(__float_as_int(v), (PAT))))

// ---- k2: self-contained qf partials: recompute qraw slice in-block, no atomics ----
__global__ __launch_bounds__(512) void k2_qf(const float* __restrict__ poi,
                                             const float* __restrict__ wq1,
                                             const float* __restrict__ bq1,
                                             const float* __restrict__ wq2, float* ws) {
    __shared__ float qr[32];
    int k = blockIdx.x, t = threadIdx.x;
    int i0 = k * 32;
    int cnt = 1683 - i0; if (cnt > 32) cnt = 32;
    if (t < cnt) {
        float a = bq1[0];
#pragma unroll
        for (int j = 0; j < 24; ++j) a += poi[(i0 + t) * 24 + j] * wq1[j];
        qr[t] = a;
    }
    __syncthreads();
    float a = 0.f;
    for (int ii = 0; ii < cnt; ++ii) a += qr[ii] * wq2[(size_t)(i0 + ii) * 512 + t];
    ws[QFP_OFF + k * 512 + t] = a;
}

// ---- k3: qf = bq2 + sum partials; qkvec (pre-scaled); blocks 8-15 also init row=bo ----
__global__ void k3_qkvec(const float* __restrict__ wk, const float* __restrict__ bq2,
                         const float* __restrict__ bo, float* ws) {
    __shared__ float qf[512];
    int t = threadIdx.x, bid = blockIdx.x;
    for (int o = t; o < 512; o += 256) {
        float s = bq2[o];
        for (int k = 0; k < 53; ++k) s += ws[QFP_OFF + k * 512 + o];
        qf[o] = s;
    }
    __syncthreads();
    int idx = bid * 256 + t;
    int h = idx >> 9, c = idx & 511;
    float a = 0.f;
#pragma unroll 8
    for (int e = 0; e < 64; ++e) a += qf[h * 64 + e] * wk[(size_t)c * 512 + h * 64 + e];
    ws[QKV_OFF + idx] = 0.125f * a;
    if (bid >= 8) {
        int b = bid - 8;
        ws[ROW_OFF + b * 512 + t]       = bo[t];
        ws[ROW_OFF + b * 512 + 256 + t] = bo[256 + t];
    }
}

// ---- kF: fused pass, 2 rows/iter (R15 shape), DPP fold-by-head reduce.
// Head ownership bits {0,1,3}: fold = xor1(DPP), xor2(DPP), xor8(DPP row_ror:8);
// sums = xor4, xor16 (ds_swizzle) + xor32 (shfl). Chain latency ~2.5x shorter.
// (256,2): only proven no-spill big-regfile config (R7/R12/R14 spill lessons).
__global__ __launch_bounds__(256, 2) void kF(const float* __restrict__ x, float* __restrict__ ws) {
    __shared__ float num_s[4096];
    __shared__ float den_s[8];
    int t = threadIdx.x;
    int lane = t & 63, w = t >> 6;        // 4 waves
    int b = blockIdx.x >> 6, slot = blockIdx.x & 63;
    int wslot = slot * 4 + w;             // 0..255 row streams per batch

    float4 qa[8], qb[8];
    {
        const float4* qg4 = (const float4*)(ws + QKV_OFF);
#pragma unroll
        for (int h = 0; h < 8; ++h) {
            qa[h] = qg4[h * 128 + lane * 2];
            qb[h] = qg4[h * 128 + lane * 2 + 1];
        }
    }

    const int b0 = lane & 1, b1 = (lane >> 1) & 1, b3 = (lane >> 3) & 1;
    float num[8][8] = {{0.f}};
    float den_own = 0.f;                  // running den for head (lane&3)|((lane&8)>>1)

    const float4* xp = (const float4*)(x + (size_t)b * L_SEQ * 512);

    for (int r = wslot; r < L_SEQ; r += 512) {     // 16 iters; rows r and r+256
        int r2 = r + 256;
        float4 xa1 = xp[(size_t)r  * 128 + lane * 2];
        float4 xb1 = xp[(size_t)r  * 128 + lane * 2 + 1];
        float4 xa2 = xp[(size_t)r2 * 128 + lane * 2];
        float4 xb2 = xp[(size_t)r2 * 128 + lane * 2 + 1];

        float p1[8], p2[8];
#pragma unroll
        for (int h = 0; h < 8; ++h) {
            p1[h] = xa1.x * qa[h].x + xa1.y * qa[h].y + xa1.z * qa[h].z + xa1.w * qa[h].w
                  + xb1.x * qb[h].x + xb1.y * qb[h].y + xb1.z * qb[h].z + xb1.w * qb[h].w;
            p2[h] = xa2.x * qa[h].x + xa2.y * qa[h].y + xa2.z * qa[h].z + xa2.w * qa[h].w
                  + xb2.x * qb[h].x + xb2.y * qb[h].y + xb2.z * qb[h].z + xb2.w * qb[h].w;
        }

        // fold level A: head bit0 (xor1, quad_perm)
        float vA0 = DPPADD(b0 ? p1[1] : p1[0], b0 ? p1[0] : p1[1], 0xB1);
        float vA1 = DPPADD(b0 ? p1[3] : p1[2], b0 ? p1[2] : p1[3], 0xB1);
        float vA2 = DPPADD(b0 ? p1[5] : p1[4], b0 ? p1[4] : p1[5], 0xB1);
        float vA3 = DPPADD(b0 ? p1[7] : p1[6], b0 ? p1[6] : p1[7], 0xB1);
        float vB0 = DPPADD(b0 ? p2[1] : p2[0], b0 ? p2[0] : p2[1], 0xB1);
        float vB1 = DPPADD(b0 ? p2[3] : p2[2], b0 ? p2[2] : p2[3], 0xB1);
        float vB2 = DPPADD(b0 ? p2[5] : p2[4], b0 ? p2[4] : p2[5], 0xB1);
        float vB3 = DPPADD(b0 ? p2[7] : p2[6], b0 ? p2[6] : p2[7], 0xB1);
        // fold level B: head bit1 (xor2, quad_perm)
        float uA0 = DPPADD(b1 ? vA1 : vA0, b1 ? vA0 : vA1, 0x4E);
        float uA1 = DPPADD(b1 ? vA3 : vA2, b1 ? vA2 : vA3, 0x4E);
        float uB0 = DPPADD(b1 ? vB1 : vB0, b1 ? vB0 : vB1, 0x4E);
        float uB1 = DPPADD(b1 ? vB3 : vB2, b1 ? vB2 : vB3, 0x4E);
        // fold level C: head bit2 <- lane bit3 (xor8 == row_ror:8 within 16)
        float sA = DPPADD(b3 ? uA1 : uA0, b3 ? uA0 : uA1, 0x128);
        float sB = DPPADD(b3 ? uB1 : uB0, b3 ? uB0 : uB1, 0x128);
        // pure sums over remaining lane bits 2, 4, 5
        sA = SWZADD(sA, 0x101F);  sB = SWZADD(sB, 0x101F);   // xor4
        sA = SWZADD(sA, 0x401F);  sB = SWZADD(sB, 0x401F);   // xor16
        sA += __shfl_xor(sA, 32, 64);
        sB += __shfl_xor(sB, 32, 64);

        float wgA = __expf(sA), wgB = __expf(sB);   // pre-scaled logits; |s| small
        den_own += wgA + wgB;

        // broadcast: head h lives in lane (h&3)|((h&4)<<1) of each 32-group
        float wa[8], wb[8];
        wa[0] = SWZ(wgA,   0); wa[1] = SWZ(wgA,  32); wa[2] = SWZ(wgA,  64); wa[3] = SWZ(wgA,  96);
        wa[4] = SWZ(wgA, 256); wa[5] = SWZ(wgA, 288); wa[6] = SWZ(wgA, 320); wa[7] = SWZ(wgA, 352);
        wb[0] = SWZ(wgB,   0); wb[1] = SWZ(wgB,  32); wb[2] = SWZ(wgB,  64); wb[3] = SWZ(wgB,  96);
        wb[4] = SWZ(wgB, 256); wb[5] = SWZ(wgB, 288); wb[6] = SWZ(wgB, 320); wb[7] = SWZ(wgB, 352);

#pragma unroll
        for (int h = 0; h < 8; ++h) {
            num[h][0] += wa[h] * xa1.x + wb[h] * xa2.x;
            num[h][1] += wa[h] * xa1.y + wb[h] * xa2.y;
            num[h][2] += wa[h] * xa1.z + wb[h] * xa2.z;
            num[h][3] += wa[h] * xa1.w + wb[h] * xa2.w;
            num[h][4] += wa[h] * xb1.x + wb[h] * xb2.x;
            num[h][5] += wa[h] * xb1.y + wb[h] * xb2.y;
            num[h][6] += wa[h] * xb1.z + wb[h] * xb2.z;
            num[h][7] += wa[h] * xb1.w + wb[h] * xb2.w;
        }
    }

    // staged deterministic block reduction across the 4 waves
    for (int wi = 0; wi < 4; ++wi) {
        if (w == wi) {
#pragma unroll
            for (int h = 0; h < 8; ++h) {
                int base = h * 512 + lane * 8;
                if (wi == 0) {
#pragma unroll
                    for (int j = 0; j < 8; ++j) num_s[base + j] = num[h][j];
                } else {
#pragma unroll
                    for (int j = 0; j < 8; ++j) num_s[base + j] += num[h][j];
                }
            }
            if ((lane & 52) == 0) {               // lanes 0,1,2,3,8,9,10,11
                int hh = (lane & 3) | ((lane & 8) >> 1);
                if (wi == 0) den_s[hh] = den_own; else den_s[hh] += den_own;
            }
        }
        __syncthreads();
    }
    // coalesced partial-slot store (no atomics)
    float4* yp4 = (float4*)(ws + YPART_OFF + (size_t)blockIdx.x * 4096);
    const float4* ns4 = (const float4*)num_s;
#pragma unroll
    for (int k = 0; k < 4; ++k) yp4[k * 256 + t] = ns4[k * 256 + t];
    if (t < 8) ws[DPART_OFF + blockIdx.x * 8 + t] = den_s[t];
}

// ---- kVR: merged tail. block=(b,h): den+yn reduce, V chunk = yn_h.wv+bv, then
// row[b,:] += V_chunk.wo (atomic, row init'd to bo by k3). One launch less. ----
__global__ __launch_bounds__(512) void kVR(const float* __restrict__ wv,
                                           const float* __restrict__ bv,
                                           const float* __restrict__ wo, float* ws) {
    __shared__ float red[512];
    __shared__ float yn_s[512];
    __shared__ float V_s[64];
    int b = blockIdx.x >> 3, h = blockIdx.x & 7;
    int t = threadIdx.x;
    // den[b][h]: 64 slot values
    red[t] = (t < 64) ? ws[DPART_OFF + (size_t)(b * 64 + t) * 8 + h] : 0.f;
    __syncthreads();
#pragma unroll
    for (int off = 32; off >= 1; off >>= 1) {
        if (t < off) red[t] += red[t + off];
        __syncthreads();
    }
    float dinv = 1.f / red[0];
    __syncthreads();
    // yn[h][t]: sum 64 slots
    {
        float s = 0.f;
        const float* yp = ws + YPART_OFF + (size_t)(b * 64) * 4096 + h * 512 + t;
#pragma unroll 8
        for (int sl = 0; sl < 64; ++sl) s += yp[(size_t)sl * 4096];
        yn_s[t] = s * dinv;
    }
    __syncthreads();
    // V chunk: o_local = t&63, c-slice = t>>6
    {
        int ol = t & 63, sl = t >> 6;
        float acc = 0.f;
        const float* yb = yn_s + sl * 64;
        const float* wvp = wv + (size_t)(sl * 64) * 512 + h * 64 + ol;
#pragma unroll 8
        for (int ci = 0; ci < 64; ++ci) acc += yb[ci] * wvp[(size_t)ci * 512];
        red[t] = acc;
    }
    __syncthreads();
    if (t < 64) {
        float acc = bv[h * 64 + t];
#pragma unroll
        for (int sl = 0; sl < 8; ++sl) acc += red[sl * 64 + t];
        V_s[t] = acc;
    }
    __syncthreads();
    // row partial: j = t
    {
        float acc = 0.f;
#pragma unroll 8
        for (int oi = 0; oi < 64; ++oi) acc += V_s[oi] * wo[(size_t)(h * 64 + oi) * 512 + t];
        atomicAdd(ws + ROW_OFF + b * 512 + t, acc);
    }
}

// ---- k9: broadcast out[b,l,:] = row[b,:]  (nontemporal float4 stores) ----
__global__ __launch_bounds__(256) void k9_out(const float* __restrict__ ws, float* __restrict__ out) {
    const f4v* row4 = (const f4v*)(ws + ROW_OFF);
    f4v* out4 = (f4v*)out;
    size_t stride = (size_t)gridDim.x * blockDim.x;
    for (size_t g = (size_t)blockIdx.x * blockDim.x + threadIdx.x; g < 8388608ull; g += stride) {
        int b = (int)(g >> 20);          // 8192 rows * 128 float4/row = 2^20 per batch
        int q = (int)(g & 127);
        f4v v = row4[b * 128 + q];
        __builtin_nontemporal_store(v, &out4[g]);
    }
}

extern "C" void kernel_launch(void* const* d_in, const int* in_sizes, int n_in,
                              void* d_out, int out_size, void* d_ws, size_t ws_size,
                              hipStream_t stream) {
    const float* x   = (const float*)d_in[0];
    const float* poi = (const float*)d_in[1];
    const float* wq1 = (const float*)d_in[2];
    const float* bq1 = (const float*)d_in[3];
    const float* wq2 = (const float*)d_in[4];
    const float* bq2 = (const float*)d_in[5];
    const float* wk  = (const float*)d_in[6];
    const float* bk  = (const float*)d_in[7];
    const float* wv  = (const float*)d_in[8];
    const float* bv  = (const float*)d_in[9];
    const float* wo  = (const float*)d_in[10];
    const float* bo  = (const float*)d_in[11];
    float* ws  = (float*)d_ws;
    float* out = (float*)d_out;
    (void)bk;

    k2_qf<<<53, 512, 0, stream>>>(poi, wq1, bq1, wq2, ws);
    k3_qkvec<<<16, 256, 0, stream>>>(wk, bq2, bo, ws);
    kF<<<512, 256, 0, stream>>>(x, ws);
    kVR<<<64, 512, 0, stream>>>(wv, bv, wo, ws);
    k9_out<<<2048, 256, 0, stream>>>(ws, out);
}